// Round 1
// baseline (91.155 us; speedup 1.0000x reference)
//
#include <hip/hip_runtime.h>

#if defined(__has_builtin)
#  if __has_builtin(__builtin_amdgcn_exp2f)
#    define EXP2F(x) __builtin_amdgcn_exp2f(x)
#  else
#    define EXP2F(x) exp2f(x)
#  endif
#else
#  define EXP2F(x) exp2f(x)
#endif

constexpr int NPIX  = 262144;
constexpr int NC    = 1024;
constexpr int NG    = 256;
constexpr int BLOCK = 256;
constexpr int PPT   = 2;                       // pixel groups per thread
constexpr int PIX_PER_BLOCK = BLOCK * PPT;     // 512

__global__ __launch_bounds__(BLOCK, 2)
void kbpa_fused(const float* __restrict__ alphas,
                const float* __restrict__ betas,
                const float* __restrict__ K,
                const float* __restrict__ pixels,
                const float* __restrict__ centers,
                const float* __restrict__ sdp2p,
                float* __restrict__ out)
{
    __shared__ float4 cpack[NC];               // (cx, cy, f*|c|^2, alpha) — 16 KB

    const int tid  = threadIdx.x;
    const int lane = tid & 63;
    const int wave = tid >> 6;
    const int blockBase = blockIdx.x * PIX_PER_BLOCK;

    const float sdp2 = sdp2p[0];
    const float f    = -1.44269504088896340736f / (2.0f * sdp2); // -log2(e)/(2*sdp2)
    const float m2f  = -2.0f * f;

    // pack centers into LDS
    for (int c = tid; c < NC; c += BLOCK) {
        const float cx = centers[2 * c + 0];
        const float cy = centers[2 * c + 1];
        cpack[c] = make_float4(cx, cy, (cx * cx + cy * cy) * f, alphas[c]);
    }

    // per-lane betas fragment: rows 4*lane .. 4*lane+3, both columns
    // betas row-major (256,2): bf[2l]   = {b[4l][0],   b[4l][1],   b[4l+1][0], b[4l+1][1]}
    //                          bf[2l+1] = {b[4l+2][0], b[4l+2][1], b[4l+3][0], b[4l+3][1]}
    const float4* bf = (const float4*)betas;
    const float4 b0 = bf[2 * lane + 0];
    const float4 b1 = bf[2 * lane + 1];

    __syncthreads();

    for (int ph = 0; ph < PPT; ++ph) {
        // wave-parity phase swap: half the waves stream K while the other half
        // run the centers loop -> memory and VALU phases overlap on each CU
        const int g = ph ^ (wave & 1);
        const int gBase = blockBase + g * BLOCK;
        const int p = gBase + tid;
        const float2 mypix = ((const float2*)pixels)[p];

        // ---- stage A: wave-cooperative deformed coords (coalesced K stream) ----
        float dx = 0.f, dy = 0.f;
        const int rowBase = gBase + wave * 64;
        #pragma unroll 4
        for (int i = 0; i < 64; ++i) {
            const float4 k = ((const float4*)(K + (size_t)(rowBase + i) * NG))[lane];
            float s0 = k.x * b0.x + k.y * b0.z;
            float s1 = k.x * b0.y + k.y * b0.w;
            s0 = fmaf(k.z, b1.x, s0);
            s0 = fmaf(k.w, b1.z, s0);
            s1 = fmaf(k.z, b1.y, s1);
            s1 = fmaf(k.w, b1.w, s1);
            #pragma unroll
            for (int m = 32; m; m >>= 1) {
                s0 += __shfl_xor(s0, m, 64);
                s1 += __shfl_xor(s1, m, 64);
            }
            if (lane == i) { dx = mypix.x - s0; dy = mypix.y - s1; }
        }

        // ---- stage B: 1024 centers from LDS (broadcast reads) ----
        const float pn2f = (dx * dx + dy * dy) * f;  // hoisted: exp2(f*|d|^2)
        const float dxs  = m2f * dx;
        const float dys  = m2f * dy;
        float acc = 0.f;
        #pragma unroll 8
        for (int c = 0; c < NC; ++c) {
            const float4 cp = cpack[c];
            const float arg = fmaf(dxs, cp.x, fmaf(dys, cp.y, cp.z));
            acc = fmaf(cp.w, EXP2F(arg), acc);
        }
        out[p] = acc * EXP2F(pn2f);
    }
}

extern "C" void kernel_launch(void* const* d_in, const int* in_sizes, int n_in,
                              void* d_out, int out_size, void* d_ws, size_t ws_size,
                              hipStream_t stream)
{
    const float* alphas  = (const float*)d_in[0];
    const float* betas   = (const float*)d_in[1];
    const float* K       = (const float*)d_in[2];
    const float* pixels  = (const float*)d_in[3];
    const float* centers = (const float*)d_in[4];
    const float* sdp2    = (const float*)d_in[5];
    float* outp          = (float*)d_out;

    dim3 grid(NPIX / PIX_PER_BLOCK);  // 512 blocks -> 2 blocks/CU
    dim3 block(BLOCK);
    hipLaunchKernelGGL(kbpa_fused, grid, block, 0, stream,
                       alphas, betas, K, pixels, centers, sdp2, outp);
}